// Round 9
// baseline (86.598 us; speedup 1.0000x reference)
//
#include <hip/hip_runtime.h>
#include <hip/hip_bf16.h>

typedef __attribute__((ext_vector_type(8))) short bf16x8;   // 8 bf16 (MFMA A/B frag)
typedef __attribute__((ext_vector_type(4))) float f32x4;    // MFMA C/D frag

static __device__ __forceinline__ unsigned short f2b(float f) {
  union { __hip_bfloat16 h; unsigned short u; } cv;
  cv.h = __float2bfloat16(f);
  return cv.u;
}

static __device__ __forceinline__ bf16x8 pack8(float4 a, float4 b) {
  bf16x8 r;
  r[0] = (short)f2b(a.x); r[1] = (short)f2b(a.y); r[2] = (short)f2b(a.z); r[3] = (short)f2b(a.w);
  r[4] = (short)f2b(b.x); r[5] = (short)f2b(b.y); r[6] = (short)f2b(b.z); r[7] = (short)f2b(b.w);
  return r;
}

// ---- prep: weights -> bf16 W^T in ws ----
// wt layout (bf16): WT1 @0 (256x128), WT2 @32768 (256x256), WT3 @98304 (256x256)
__global__ void __launch_bounds__(256) gnn_prep(const float* __restrict__ W1,
                                                const float* __restrict__ W2,
                                                const float* __restrict__ W3,
                                                unsigned short* __restrict__ wt) {
  int idx = blockIdx.x * 256 + threadIdx.x;   // 0..65535
  unsigned short* wt1 = wt;
  unsigned short* wt2 = wt + 32768;
  unsigned short* wt3 = wt + 98304;
  if (idx < 32768) { int d = idx >> 8, h = idx & 255; wt1[h * 128 + d] = f2b(W1[idx]); }
  { int d = idx >> 8, h = idx & 255; wt2[h * 256 + d] = f2b(W2[idx]); wt3[h * 256 + d] = f2b(W3[idx]); }
}

// Swizzles: 16B-granule XOR by low row bits; identical write+read.
#define XS(d, colb)  ((d) * 128 + ((((colb) ^ (((d) & 15) << 4))) >> 1))   // sXT pitch 256B
#define AGS(i, colb) ((i) * 64  + ((((colb) ^ (((i) & 7)  << 4))) >> 1))   // sAggC pitch 128B

// ---- A-phase: AGG^T[d-chunk cc][i] = sum_j X^T[d][j] * adj[j][i]; grid 1x8 (wave=16 i) ----
static __device__ __forceinline__ void a_phase(int cc, const unsigned short* sXT,
                                               unsigned short* buf, const bf16x8 (&adjF)[4],
                                               int w, int l15, int l4) {
  f32x4 accA[4];
#pragma unroll
  for (int t = 0; t < 4; ++t) accA[t] = (f32x4){0.f, 0.f, 0.f, 0.f};
#pragma unroll
  for (int ks = 0; ks < 4; ++ks) {
    bf16x8 a[4];
#pragma unroll
    for (int t = 0; t < 4; ++t) {
      int dr = cc * 64 + t * 16 + l15;
      a[t] = *(const bf16x8*)&sXT[XS(dr, ks * 64 + l4 * 16)];
    }
#pragma unroll
    for (int t = 0; t < 4; ++t)
      accA[t] = __builtin_amdgcn_mfma_f32_16x16x32_bf16(a[t], adjF[ks], accA[t], 0, 0, 0);
  }
  int i = w * 16 + l15;
#pragma unroll
  for (int t = 0; t < 4; ++t) {
    int dloc = t * 16 + l4 * 4;
    f32x4 v = accA[t];
    *(ushort4*)&buf[AGS(i, 2 * dloc)] = make_ushort4(f2b(v[0]), f2b(v[1]), f2b(v[2]), f2b(v[3]));
  }
}

// ---- B-phase: accB += AGG_chunk @ W_chunk; A from LDS, B from prefetched regs ----
static __device__ __forceinline__ void b_phase(const unsigned short* buf,
                                               const bf16x8 (&wf)[2][4], f32x4 (&accB)[4][4],
                                               int l15, int l4, int wm, int wn) {
#pragma unroll
  for (int ks = 0; ks < 2; ++ks) {
    bf16x8 aB[4];
#pragma unroll
    for (int mi = 0; mi < 4; ++mi) {
      int ir = wm * 64 + mi * 16 + l15;
      aB[mi] = *(const bf16x8*)&buf[AGS(ir, ks * 64 + l4 * 16)];
    }
#pragma unroll
    for (int ni = 0; ni < 4; ++ni)
#pragma unroll
      for (int mi = 0; mi < 4; ++mi)
        accB[mi][ni] = __builtin_amdgcn_mfma_f32_16x16x32_bf16(aB[mi], wf[ks][ni], accB[mi][ni], 0, 0, 0);
  }
}

// ---- one layer: software-pipelined chunks, ONE barrier per chunk ----
// iter c: [prefetch W(c+1)->regs | A(c+1)->sAgg[nxt] | B(c) from sAgg[cur]+wf[cur]] barrier
template<int NCK>
static __device__ __forceinline__ void run_layer(const unsigned short* __restrict__ wtl,
                                                 const unsigned short* sXT, unsigned short* sAgg,
                                                 const bf16x8 (&adjF)[4], f32x4 (&accB)[4][4],
                                                 int w, int l15, int l4, int wm, int wn) {
  constexpr int Din = NCK * 64;
  bf16x8 wf[2][2][4];   // [chunk parity][ks][ni] — all indices compile-time (full unroll)
#pragma unroll
  for (int ks = 0; ks < 2; ++ks)
#pragma unroll
    for (int ni = 0; ni < 4; ++ni) {
      int hr = wn * 64 + ni * 16 + l15;
      wf[0][ks][ni] = *(const bf16x8*)(wtl + hr * Din + ks * 32 + l4 * 8);
    }
  a_phase(0, sXT, sAgg, adjF, w, l15, l4);
  __syncthreads();
#pragma unroll
  for (int c = 0; c < NCK; ++c) {
    if (c + 1 < NCK) {
#pragma unroll
      for (int ks = 0; ks < 2; ++ks)
#pragma unroll
        for (int ni = 0; ni < 4; ++ni) {
          int hr = wn * 64 + ni * 16 + l15;
          wf[(c + 1) & 1][ks][ni] =
              *(const bf16x8*)(wtl + hr * Din + (c + 1) * 64 + ks * 32 + l4 * 8);
        }
      a_phase(c + 1, sXT, sAgg + ((c + 1) & 1) * 8192, adjF, w, l15, l4);
    }
    b_phase(sAgg + (c & 1) * 8192, wf[c & 1], accB, l15, l4, wm, wn);
    __syncthreads();
  }
}

// ---- main: one block per graph, 512 thr (8 waves), 96 KB LDS, (512,2) -> 256-reg budget ----
__global__ void __launch_bounds__(512, 2) gnn_main(
    const float* __restrict__ xin, const float* __restrict__ adjg,
    const float* __restrict__ b1, const float* __restrict__ b2,
    const float* __restrict__ b3, const float* __restrict__ Wh,
    const float* __restrict__ bh, const unsigned short* __restrict__ wt,
    float* __restrict__ out) {
  __shared__ unsigned short sXT[256 * 128];   // X^T [d][j], swizzled; 64 KB
  __shared__ unsigned short sAgg[2 * 8192];   // AGG chunk dbuf [2][128][64], swizzled; 32 KB

  const int g = blockIdx.x, tid = threadIdx.x;
  const int lane = tid & 63, w = tid >> 6;    // 8 waves
  const int l15 = lane & 15, l4 = lane >> 4;
  const int wm = w & 1, wn = w >> 1;          // B-phase grid 2(i) x 4(h)

  const float* xg = xin + (size_t)g * 16384;
  const float* ag = adjg + (size_t)g * 16384;

  // ---- adj B-fragments (A-grid 1x8: wave w owns i in [w*16, w*16+16)); 16 regs ----
  bf16x8 adjF[4];
  {
    int ir = w * 16 + l15;
#pragma unroll
    for (int ks = 0; ks < 4; ++ks) {
      float4 a0 = *(const float4*)(ag + ir * 128 + ks * 32 + l4 * 8);
      float4 a1 = *(const float4*)(ag + ir * 128 + ks * 32 + l4 * 8 + 4);
      adjF[ks] = pack8(a0, a1);
    }
  }
  // ---- in-kernel X transpose: X[j][d] fp32 -> sXT[d][j] bf16 (4x4 register-blocked) ----
  {
    int db = tid & 31, jb = tid >> 5;         // 32 d-blocks x 16 j-blocks... (512thr: jb 0..15)
#pragma unroll
    for (int rep = 0; rep < 2; ++rep) {       // two j-block passes (16 jb x 2 = 32)
      int j0 = (jb + rep * 16) * 4, d0 = db * 4;
      float4 r0 = *(const float4*)(xg + (j0 + 0) * 128 + d0);
      float4 r1 = *(const float4*)(xg + (j0 + 1) * 128 + d0);
      float4 r2 = *(const float4*)(xg + (j0 + 2) * 128 + d0);
      float4 r3 = *(const float4*)(xg + (j0 + 3) * 128 + d0);
      *(ushort4*)&sXT[XS(d0 + 0, j0 * 2)] = make_ushort4(f2b(r0.x), f2b(r1.x), f2b(r2.x), f2b(r3.x));
      *(ushort4*)&sXT[XS(d0 + 1, j0 * 2)] = make_ushort4(f2b(r0.y), f2b(r1.y), f2b(r2.y), f2b(r3.y));
      *(ushort4*)&sXT[XS(d0 + 2, j0 * 2)] = make_ushort4(f2b(r0.z), f2b(r1.z), f2b(r2.z), f2b(r3.z));
      *(ushort4*)&sXT[XS(d0 + 3, j0 * 2)] = make_ushort4(f2b(r0.w), f2b(r1.w), f2b(r2.w), f2b(r3.w));
    }
  }
  __syncthreads();

  f32x4 accB[4][4];

  for (int l = 0; l < 3; ++l) {
#pragma unroll
    for (int mi = 0; mi < 4; ++mi)
#pragma unroll
      for (int ni = 0; ni < 4; ++ni) accB[mi][ni] = (f32x4){0.f, 0.f, 0.f, 0.f};

    if (l == 0) run_layer<2>(wt, sXT, sAgg, adjF, accB, w, l15, l4, wm, wn);
    else if (l == 1) run_layer<4>(wt + 32768, sXT, sAgg, adjF, accB, w, l15, l4, wm, wn);
    else run_layer<4>(wt + 98304, sXT, sAgg, adjF, accB, w, l15, l4, wm, wn);

    if (l < 2) {
      const float* bl = (l == 0) ? b1 : b2;
      // H[i][h] -> sXT[h][i] (next layer's X^T), 8B swizzled writes
#pragma unroll
      for (int ni = 0; ni < 4; ++ni) {
        int h = wn * 64 + ni * 16 + l15;
        float bias = bl[h];
#pragma unroll
        for (int mi = 0; mi < 4; ++mi) {
          int i0 = wm * 64 + mi * 16 + l4 * 4;
          f32x4 v = accB[mi][ni];
          *(ushort4*)&sXT[XS(h, 2 * i0)] = make_ushort4(
              f2b(fmaxf(v[0] + bias, 0.f)), f2b(fmaxf(v[1] + bias, 0.f)),
              f2b(fmaxf(v[2] + bias, 0.f)), f2b(fmaxf(v[3] + bias, 0.f)));
        }
      }
      __syncthreads();
    } else {
      // ---- mean pool + linear head (fp32) ----
      float* sPool = (float*)sAgg;            // run_layer ended with barrier; sAgg dead
      float ps[4];
#pragma unroll
      for (int ni = 0; ni < 4; ++ni) {
        float bias = b3[wn * 64 + ni * 16 + l15];
        float s = 0.f;
#pragma unroll
        for (int mi = 0; mi < 4; ++mi)
#pragma unroll
          for (int r = 0; r < 4; ++r) s += fmaxf(accB[mi][ni][r] + bias, 0.f);
        s += __shfl_xor(s, 16);
        s += __shfl_xor(s, 32);
        ps[ni] = s;
      }
      if (l4 == 0) {
#pragma unroll
        for (int ni = 0; ni < 4; ++ni) sPool[wm * 256 + wn * 64 + ni * 16 + l15] = ps[ni];
      }
      __syncthreads();
      if (w == 0) {
        float acc = 0.f;
#pragma unroll
        for (int q = 0; q < 4; ++q) {
          int h = lane + q * 64;
          acc += (sPool[h] + sPool[256 + h]) * Wh[h];
        }
#pragma unroll
        for (int off = 32; off > 0; off >>= 1) acc += __shfl_xor(acc, off);
        if (lane == 0) out[g] = acc * (1.0f / 128.0f) + bh[0];
      }
    }
  }
}

extern "C" void kernel_launch(void* const* d_in, const int* in_sizes, int n_in,
                              void* d_out, int out_size, void* d_ws, size_t ws_size,
                              hipStream_t stream) {
  const float* xin = (const float*)d_in[0];   // node_features [512,128,128]
  const float* adj = (const float*)d_in[1];   // adj [512,128,128]
  const float* W1  = (const float*)d_in[2];
  const float* b1  = (const float*)d_in[3];
  const float* W2  = (const float*)d_in[4];
  const float* b2  = (const float*)d_in[5];
  const float* W3  = (const float*)d_in[6];
  const float* b3  = (const float*)d_in[7];
  const float* Wh  = (const float*)d_in[8];
  const float* bh  = (const float*)d_in[9];

  unsigned short* wt = (unsigned short*)d_ws;   // 327,680 B of bf16 W^T

  gnn_prep<<<256, 256, 0, stream>>>(W1, W2, W3, wt);
  gnn_main<<<512, 512, 0, stream>>>(xin, adj, b1, b2, b3, Wh, bh, wt, (float*)d_out);
}